// Round 1
// baseline (415.718 us; speedup 1.0000x reference)
//
#include <hip/hip_runtime.h>
#include <hip/hip_bf16.h>
#include <math.h>

#define B_   8
#define G_   1024
#define M_   8
#define N_   2048
#define RBF_ 50
#define H_   128
#define PP_  28      // i<j pairs of 8
#define RPAD 52      // RBF padded to multiple of 4
#define RC_  13      // RPAD/4

// ---- workspace layout (in floats) ----
#define OFF_WLT  0
#define SZ_WT    (PP_*RC_*H_*4)            // 186368
#define OFF_WRT  (OFF_WLT + SZ_WT)
#define OFF_XC   (OFF_WRT + SZ_WT)         // 372736
#define SZ_XC    (B_*G_*M_*3)              // 196608
#define OFF_ATT  (OFF_XC + SZ_XC)          // 569344
#define SZ_ATT   (B_*H_*G_)                // 1048576
#define OFF_PART (OFF_ATT + SZ_ATT)        // 1617920
#define SZ_PART  (B_*8*H_*2)               // 16384

__device__ const int c_pi[28] = {0,0,0,0,0,0,0,1,1,1,1,1,1,2,2,2,2,2,3,3,3,3,4,4,4,5,5,6};
__device__ const int c_pj[28] = {1,2,3,4,5,6,7,2,3,4,5,6,7,3,4,5,6,7,4,5,6,7,5,6,7,6,7,7};

// K0: fold (i,j)-(j,i) weight pairs and transpose to [pp][rc][h][4] for
// coalesced float4 loads in K2. 372736 elements total (grid exact).
__global__ __launch_bounds__(256) void k_fold(const float* __restrict__ Wl,
                                              const float* __restrict__ Wr,
                                              float* __restrict__ ws) {
    int idx = blockIdx.x * 256 + threadIdx.x;
    int c = idx & 3;       int t = idx >> 2;
    int h = t & 127;       t >>= 7;
    int rc = t % 13;       t /= 13;
    int pp = t % 28;       int side = t / 28;
    if (side >= 2) return;
    int r = rc * 4 + c;
    const float* src = side ? Wr : Wl;
    float v = 0.f;
    if (r < 50) {
        int i = c_pi[pp], j = c_pj[pp];
        v = src[h*3200 + (i*8 + j)*50 + r] - src[h*3200 + (j*8 + i)*50 + r];
    }
    float* dst = ws + (side ? OFF_WRT : OFF_WLT);
    dst[((pp*13 + rc)*128 + h)*4 + c] = v;
}

// K1: xc[b,g,m,d] = sum_n W_map[g,m,n] * x[b,n,d].
// Mapping: lanes = rows (g*8+m), n sequential & uniform -> x loads scalarize;
// each lane streams its own W row contiguously (float4). n split 16 ways for
// grid parallelism; partials combined via fp32 atomics (xc memset to 0 first).
__global__ __launch_bounds__(256) void k_xc(const float* __restrict__ x,
                                            const float* __restrict__ Wm,
                                            float* __restrict__ ws) {
    float* xc = ws + OFF_XC;
    int wv = blockIdx.x * 4 + (threadIdx.x >> 6);   // 2048 waves
    int lane = threadIdx.x & 63;
    int rowgroup = wv >> 4, nslice = wv & 15;
    int row = rowgroup * 64 + lane;                 // 0..8191  (= g*8+m)
    int n0 = nslice * 128;
    float acc[24];
#pragma unroll
    for (int c = 0; c < 24; ++c) acc[c] = 0.f;
    const float* wrow = Wm + (size_t)row * 2048;
    for (int nb = 0; nb < 128; nb += 4) {
        int n = n0 + nb;
        float4 w4 = *(const float4*)(wrow + n);
#pragma unroll
        for (int k = 0; k < 4; ++k) {
            float wk = (k == 0) ? w4.x : (k == 1) ? w4.y : (k == 2) ? w4.z : w4.w;
#pragma unroll
            for (int b = 0; b < 8; ++b) {
                const float* xp = x + (size_t)(b*2048 + n + k) * 3;  // uniform -> s_load
                acc[b*3+0] += wk * xp[0];
                acc[b*3+1] += wk * xp[1];
                acc[b*3+2] += wk * xp[2];
            }
        }
    }
#pragma unroll
    for (int b = 0; b < 8; ++b)
#pragma unroll
        for (int d = 0; d < 3; ++d)
            atomicAdd(&xc[(size_t)b*24576 + row*3 + d], acc[b*3+d]);
}

// K2: fused main. One WG = 8 (b,g) pairs. Phase 1: 224 threads build
// sm[t][pp][52] (+2 zero pad) and delta[t][pp] in LDS. Phase 2: thread =
// (h, tg); per pp: A_l/A_r = <Wf[h,pp,:], sm[t,pp,:]> (sm via LDS broadcast,
// weights via coalesced float4), folded immediately into left/right[t][3].
// att[b,h,g] = <left,right> + 1e-5, stored float4 over 4 consecutive g.
__global__ __launch_bounds__(256) void k_main(float* __restrict__ ws) {
    __shared__ float  sm_s[224 * RPAD];   // 46592 B
    __shared__ float4 dlt_s[224];         //  3584 B
    const float* xc = ws + OFF_XC;
    const float4* WLT = (const float4*)(ws + OFF_WLT);
    const float4* WRT = (const float4*)(ws + OFF_WRT);
    float* att = ws + OFF_ATT;

    int tid = threadIdx.x;
    int p0 = blockIdx.x * 8;          // first flat pair index
    int b  = p0 >> 10;
    int g0 = p0 & 1023;

    if (tid < 224) {
        int t = tid / 28, pp = tid % 28;        // t*28+pp == tid
        int i = c_pi[pp], j = c_pj[pp];
        const float* xp = xc + (size_t)(b*8192 + (g0 + t)*8) * 3;
        float dx = xp[j*3+0] - xp[i*3+0];
        float dy = xp[j*3+1] - xp[i*3+1];
        float dz = xp[j*3+2] - xp[i*3+2];
        float dn = sqrtf(dx*dx + dy*dy + dz*dz + 1e-5f);
        dlt_s[tid] = make_float4(dx, dy, dz, 0.f);
        float pref = 0.f;
        if (dn < 5.0f) pref = 0.5f * (cosf(dn * 0.62831853071795865f) + 1.0f);
        float dinv = dn + 1e-5f;
        pref /= (dinv * dinv);
        float e = expf(-dn);                    // alpha = 1, CUT_LO = 0
        const float m0 = 0.006737946999085467f; // exp(-5)
        const float mstep = (1.0f - m0) / 49.0f;
        const float beta = 633.5087862829640f;
#pragma unroll
        for (int rc = 0; rc < 13; ++rc) {
            float4 v;
            float* vv = (float*)&v;
#pragma unroll
            for (int c = 0; c < 4; ++c) {
                int r = rc * 4 + c;
                float val = 0.f;
                if (r < 50) {
                    float dm = e - (m0 + (float)r * mstep);
                    val = pref * expf(-beta * dm * dm);
                }
                vv[c] = val;
            }
            *(float4*)&sm_s[tid * RPAD + rc * 4] = v;
        }
    }
    __syncthreads();

    int h = tid & 127, tg = tid >> 7;
    float aLx[4], aLy[4], aLz[4], aRx[4], aRy[4], aRz[4];
#pragma unroll
    for (int t = 0; t < 4; ++t) { aLx[t]=aLy[t]=aLz[t]=0.f; aRx[t]=aRy[t]=aRz[t]=0.f; }

    for (int pp = 0; pp < 28; ++pp) {
        float Al[4] = {0,0,0,0}, Ar[4] = {0,0,0,0};
#pragma unroll
        for (int rc = 0; rc < 13; ++rc) {
            float4 wl = WLT[(pp*13 + rc)*128 + h];   // coalesced across h
            float4 wr = WRT[(pp*13 + rc)*128 + h];
#pragma unroll
            for (int t = 0; t < 4; ++t) {
                const float4 s = *(const float4*)&sm_s[((tg*4 + t)*28 + pp)*RPAD + rc*4];
                Al[t] += wl.x*s.x + wl.y*s.y + wl.z*s.z + wl.w*s.w;
                Ar[t] += wr.x*s.x + wr.y*s.y + wr.z*s.z + wr.w*s.w;
            }
        }
#pragma unroll
        for (int t = 0; t < 4; ++t) {
            float4 dl = dlt_s[(tg*4 + t)*28 + pp];
            aLx[t] += Al[t]*dl.x; aLy[t] += Al[t]*dl.y; aLz[t] += Al[t]*dl.z;
            aRx[t] += Ar[t]*dl.x; aRy[t] += Ar[t]*dl.y; aRz[t] += Ar[t]*dl.z;
        }
    }
    float4 o;
    float* ov = (float*)&o;
#pragma unroll
    for (int t = 0; t < 4; ++t)
        ov[t] = aLx[t]*aRx[t] + aLy[t]*aRy[t] + aLz[t]*aRz[t] + 1e-5f;
    *(float4*)&att[(size_t)(b*128 + h)*1024 + g0 + tg*4] = o;
}

// K3: partial online logsumexp over g. Grid 64 = (b, gblk); each thread does
// 64 g's worth, halves combined in LDS -> part[b][gblk][h] = (m, s).
__global__ __launch_bounds__(256) void k_lse(float* __restrict__ ws) {
    const float* att = ws + OFF_ATT;
    float* part = ws + OFF_PART;
    int blk = blockIdx.x;
    int b = blk >> 3, gblk = blk & 7;
    int tid = threadIdx.x;
    int h = tid & 127, gh = tid >> 7;
    const float* p = att + (size_t)(b*128 + h)*1024 + gblk*128 + gh*64;
    float m = -1e30f, s = 0.f;
    for (int q = 0; q < 16; ++q) {
        float4 v4 = *(const float4*)(p + q*4);
#pragma unroll
        for (int k = 0; k < 4; ++k) {
            float v = ((float*)&v4)[k];
            float nm = fmaxf(m, v);
            s = s * expf(m - nm) + expf(v - nm);
            m = nm;
        }
    }
    __shared__ float mm[256], ss[256];
    mm[tid] = m; ss[tid] = s;
    __syncthreads();
    if (gh == 0) {
        float m2 = mm[tid + 128], s2 = ss[tid + 128];
        float Mv = fmaxf(m, m2);
        float Sv = s * expf(m - Mv) + s2 * expf(m2 - Mv);
        *(float2*)&part[((size_t)(b*8 + gblk)*128 + h)*2] = make_float2(Mv, Sv);
    }
}

// K4: combine partials -> lse[b][h], then fc1+silu+fc2 -> out[b].
__global__ __launch_bounds__(128) void k_mlp(const float* __restrict__ ws,
                                             const float* __restrict__ f1w,
                                             const float* __restrict__ f1b,
                                             const float* __restrict__ f2w,
                                             const float* __restrict__ f2b,
                                             float* __restrict__ out) {
    const float* part = ws + OFF_PART;
    int b = blockIdx.x, h = threadIdx.x;
    float ms[8], sv[8], Mv = -1e30f;
#pragma unroll
    for (int k = 0; k < 8; ++k) {
        float2 v = *(const float2*)&part[((size_t)(b*8 + k)*128 + h)*2];
        ms[k] = v.x; sv[k] = v.y;
        Mv = fmaxf(Mv, v.x);
    }
    float Sv = 0.f;
#pragma unroll
    for (int k = 0; k < 8; ++k) Sv += sv[k] * expf(ms[k] - Mv);
    float lse = Mv + logf(Sv);
    __shared__ float ls[128];
    ls[h] = lse;
    __syncthreads();
    float acc = f1b[h];
    for (int k = 0; k < 128; ++k) acc += f1w[h*128 + k] * ls[k];
    float v = acc / (1.f + expf(-acc));     // silu
    __shared__ float red[128];
    red[h] = v * f2w[h];
    __syncthreads();
    for (int st = 64; st > 0; st >>= 1) {
        if (h < st) red[h] += red[h + st];
        __syncthreads();
    }
    if (h == 0) out[b] = red[0] + f2b[0];
}

extern "C" void kernel_launch(void* const* d_in, const int* in_sizes, int n_in,
                              void* d_out, int out_size, void* d_ws, size_t ws_size,
                              hipStream_t stream) {
    const float* x   = (const float*)d_in[0];
    const float* Wm  = (const float*)d_in[1];
    const float* Wl  = (const float*)d_in[2];
    const float* Wr  = (const float*)d_in[3];
    const float* f1w = (const float*)d_in[4];
    const float* f1b = (const float*)d_in[5];
    const float* f2w = (const float*)d_in[6];
    const float* f2b = (const float*)d_in[7];
    float* ws  = (float*)d_ws;
    float* out = (float*)d_out;

    // xc accumulated with atomics -> zero it (ws is re-poisoned every launch)
    hipMemsetAsync(ws + OFF_XC, 0, SZ_XC * sizeof(float), stream);

    k_fold<<<1456, 256, 0, stream>>>(Wl, Wr, ws);
    k_xc  <<<512,  256, 0, stream>>>(x, Wm, ws);
    k_main<<<1024, 256, 0, stream>>>(ws);
    k_lse <<<64,   256, 0, stream>>>(ws);
    k_mlp <<<8,    128, 0, stream>>>(ws, f1w, f1b, f2w, f2b, out);
}